// Round 1
// baseline (696.897 us; speedup 1.0000x reference)
//
#include <hip/hip_runtime.h>
#include <math.h>

#define BATCH 4
#define CH    64
#define NPOS  4096   // 64*64
#define NGRP  8
#define CPG   8      // CH / NGRP
#define GEPS  1e-5f

// ---------------------------------------------------------------------------
// Kernel 1: GroupNorm statistics. One block per (b, g); the group's 8
// channels are contiguous in [B][C][N] layout -> 32768 contiguous floats.
// stats[bg*2] = mean, stats[bg*2+1] = rsqrt(var + eps)
// ---------------------------------------------------------------------------
__global__ __launch_bounds__(256) void gn_stats_kernel(const float* __restrict__ x,
                                                       float* __restrict__ stats) {
    const int bg = blockIdx.x;                       // 0..31
    const float* xp = x + (size_t)bg * CPG * NPOS;   // (b*NGRP+g)*CPG*NPOS
    float s1 = 0.f, s2 = 0.f;
    for (int i = threadIdx.x; i < CPG * NPOS; i += 256) {
        float t = xp[i];
        s1 += t;
        s2 += t * t;
    }
    __shared__ float sh1[256], sh2[256];
    const int tid = threadIdx.x;
    sh1[tid] = s1;
    sh2[tid] = s2;
    __syncthreads();
    for (int off = 128; off > 0; off >>= 1) {
        if (tid < off) {
            sh1[tid] += sh1[tid + off];
            sh2[tid] += sh2[tid + off];
        }
        __syncthreads();
    }
    if (tid == 0) {
        const float inv = 1.0f / (float)(CPG * NPOS);
        float mean = sh1[0] * inv;
        float var  = sh2[0] * inv - mean * mean;
        stats[bg * 2]     = mean;
        stats[bg * 2 + 1] = rsqrtf(var + GEPS);
    }
}

// ---------------------------------------------------------------------------
// Kernel 2: fused GroupNorm-apply + Q/K/V 1x1 convs.
// One thread per (b, n). xn[64] lives in registers (fully unrolled index).
// W* read directly from global with wave-uniform indices -> scalar loads.
// Outputs stored TRANSPOSED: q_t/k_t/v_t are [B][CH][N] so stores here and
// tile loads in the attention kernel are coalesced.
// q gets (.. + bq) * 0.125  (folds the 1/sqrt(64) softmax scale).
// ---------------------------------------------------------------------------
__global__ __launch_bounds__(256) void qkv_gen_kernel(
    const float* __restrict__ x, const float* __restrict__ stats,
    const float* __restrict__ gamma, const float* __restrict__ beta,
    const float* __restrict__ Wq, const float* __restrict__ bq,
    const float* __restrict__ Wk, const float* __restrict__ bk,
    const float* __restrict__ Wv, const float* __restrict__ bv,
    float* __restrict__ q_t, float* __restrict__ k_t, float* __restrict__ v_t)
{
    __shared__ float st[64];   // 32 groups * {mean, rstd}
    const int tid = threadIdx.x;
    if (tid < 64) st[tid] = stats[tid];
    __syncthreads();

    const int gidx = blockIdx.x * 256 + tid;   // 0 .. B*N-1
    const int b = gidx >> 12;                  // / 4096
    const int n = gidx & (NPOS - 1);

    const float* xp = x + (size_t)b * CH * NPOS + n;
    float xn[CH];
    const int bg0 = b * NGRP;
#pragma unroll
    for (int c = 0; c < CH; ++c) {
        float mean = st[(bg0 + (c >> 3)) * 2];
        float rstd = st[(bg0 + (c >> 3)) * 2 + 1];
        xn[c] = (xp[(size_t)c * NPOS] - mean) * rstd * gamma[c] + beta[c];
    }

    for (int o = 0; o < CH; ++o) {
        float aq = 0.f, ak = 0.f, av = 0.f;
#pragma unroll
        for (int c = 0; c < CH; ++c) {
            float xv = xn[c];
            aq = fmaf(Wq[o * CH + c], xv, aq);
            ak = fmaf(Wk[o * CH + c], xv, ak);
            av = fmaf(Wv[o * CH + c], xv, av);
        }
        size_t addr = ((size_t)b * CH + o) * NPOS + n;   // coalesced across lanes
        q_t[addr] = (aq + bq[o]) * 0.125f;
        k_t[addr] = ak + bk[o];
        v_t[addr] = av + bv[o];
    }
}

// ---------------------------------------------------------------------------
// Kernel 3: flash attention over n=4096 keys + fused proj + bias + residual.
// One block per (b, 64-query tile): grid = 4*64 = 256 blocks, 256 threads.
// LDS tiles stored [c][pos] with +1 pad (2-way LDS conflicts only = free).
// S/P tile aliases the K tile (extra barrier between S-compute and S-write).
// ---------------------------------------------------------------------------
__global__ __launch_bounds__(256) void attn_flash_kernel(
    const float* __restrict__ q_t, const float* __restrict__ k_t,
    const float* __restrict__ v_t, const float* __restrict__ x,
    const float* __restrict__ Wp, const float* __restrict__ bp,
    float* __restrict__ out)
{
    __shared__ float Qs[64][65];    // Qs[c][i]   : channel-major
    __shared__ float KSs[64][65];   // K tile [c][j]; later aliased as P [i][j]
    __shared__ float Vs[64][65];    // Vs[c][j]
    __shared__ float mrow[64], lrow[64], srow[64];

    const int tid = threadIdx.x;
    const int b  = blockIdx.x >> 6;
    const int q0 = (blockIdx.x & 63) * 64;

    const float* qb = q_t + (size_t)b * CH * NPOS;   // [c][n]
    const float* kb = k_t + (size_t)b * CH * NPOS;
    const float* vb = v_t + (size_t)b * CH * NPOS;

    // ---- load Q tile: Qs[c][i] = q_t[b][c][q0+i] (float4 coalesced) ----
#pragma unroll
    for (int r = 0; r < 4; ++r) {
        int idx = tid + r * 256;        // 0..1023
        int c   = idx >> 4;             // 0..63
        int j4  = (idx & 15) << 2;      // 0..60
        float4 t = *(const float4*)(qb + (size_t)c * NPOS + q0 + j4);
        Qs[c][j4] = t.x; Qs[c][j4 + 1] = t.y; Qs[c][j4 + 2] = t.z; Qs[c][j4 + 3] = t.w;
    }
    if (tid < 64) { mrow[tid] = -1e30f; lrow[tid] = 0.0f; }

    const int ti = tid >> 4;    // 0..15 : query sub-block
    const int tj = tid & 15;    // 0..15 : key / channel sub-block
    float oacc[4][4];
#pragma unroll
    for (int r = 0; r < 4; ++r)
#pragma unroll
        for (int s = 0; s < 4; ++s) oacc[r][s] = 0.0f;

    __syncthreads();

    for (int kt = 0; kt < 64; ++kt) {
        const int m0 = kt * 64;
        // ---- load K and V tiles (float4 coalesced reads, scalar LDS stores) ----
#pragma unroll
        for (int r = 0; r < 4; ++r) {
            int idx = tid + r * 256;
            int c   = idx >> 4;
            int j4  = (idx & 15) << 2;
            float4 t = *(const float4*)(kb + (size_t)c * NPOS + m0 + j4);
            KSs[c][j4] = t.x; KSs[c][j4 + 1] = t.y; KSs[c][j4 + 2] = t.z; KSs[c][j4 + 3] = t.w;
            float4 u = *(const float4*)(vb + (size_t)c * NPOS + m0 + j4);
            Vs[c][j4] = u.x; Vs[c][j4 + 1] = u.y; Vs[c][j4 + 2] = u.z; Vs[c][j4 + 3] = u.w;
        }
        __syncthreads();

        // ---- S = Q^T K : 4x4 register tile per thread ----
        float sacc[4][4];
#pragma unroll
        for (int r = 0; r < 4; ++r)
#pragma unroll
            for (int s = 0; s < 4; ++s) sacc[r][s] = 0.0f;

        for (int c = 0; c < CH; ++c) {
            float qv[4], kv[4];
#pragma unroll
            for (int r = 0; r < 4; ++r) qv[r] = Qs[c][ti * 4 + r];
#pragma unroll
            for (int s = 0; s < 4; ++s) kv[s] = KSs[c][tj * 4 + s];
#pragma unroll
            for (int r = 0; r < 4; ++r)
#pragma unroll
                for (int s = 0; s < 4; ++s) sacc[r][s] = fmaf(qv[r], kv[s], sacc[r][s]);
        }
        __syncthreads();   // everyone done reading K tile (we overwrite it with S)

#pragma unroll
        for (int r = 0; r < 4; ++r)
#pragma unroll
            for (int s = 0; s < 4; ++s) KSs[ti * 4 + r][tj * 4 + s] = sacc[r][s];
        __syncthreads();

        // ---- online softmax: 4 threads per row ----
        {
            int row = tid >> 2, seg = tid & 3;
            int j0 = seg * 16;
            float mx = -1e30f;
#pragma unroll
            for (int jj = 0; jj < 16; ++jj) mx = fmaxf(mx, KSs[row][j0 + jj]);
            mx = fmaxf(mx, __shfl_xor(mx, 1));
            mx = fmaxf(mx, __shfl_xor(mx, 2));
            float mold = mrow[row];
            float mnew = fmaxf(mold, mx);
            float sum = 0.0f;
#pragma unroll
            for (int jj = 0; jj < 16; ++jj) {
                float p = __expf(KSs[row][j0 + jj] - mnew);
                KSs[row][j0 + jj] = p;
                sum += p;
            }
            sum += __shfl_xor(sum, 1);
            sum += __shfl_xor(sum, 2);
            if (seg == 0) {
                float sc = __expf(mold - mnew);
                lrow[row] = lrow[row] * sc + sum;
                mrow[row] = mnew;
                srow[row] = sc;
            }
        }
        __syncthreads();

        // ---- O = O*scale + P V : 4x4 register tile per thread ----
        {
            float sc[4];
#pragma unroll
            for (int r = 0; r < 4; ++r) sc[r] = srow[ti * 4 + r];
#pragma unroll
            for (int r = 0; r < 4; ++r)
#pragma unroll
                for (int s = 0; s < 4; ++s) oacc[r][s] *= sc[r];
            for (int j = 0; j < 64; ++j) {
                float pv[4], vv[4];
#pragma unroll
                for (int r = 0; r < 4; ++r) pv[r] = KSs[ti * 4 + r][j];
#pragma unroll
                for (int s = 0; s < 4; ++s) vv[s] = Vs[tj * 4 + s][j];
#pragma unroll
                for (int r = 0; r < 4; ++r)
#pragma unroll
                    for (int s = 0; s < 4; ++s) oacc[r][s] = fmaf(pv[r], vv[s], oacc[r][s]);
            }
        }
        __syncthreads();   // before next tile overwrites K/V
    }

    // ---- normalize by l and stash attention output [i][c] in KSs ----
    {
        float li[4];
#pragma unroll
        for (int r = 0; r < 4; ++r) li[r] = 1.0f / lrow[ti * 4 + r];
#pragma unroll
        for (int r = 0; r < 4; ++r)
#pragma unroll
            for (int s = 0; s < 4; ++s) KSs[ti * 4 + r][tj * 4 + s] = oacc[r][s] * li[r];
    }
    __syncthreads();

    // ---- fused output projection + bias + residual ----
    {
        const int i   = tid & 63;            // position within tile (coalesced writes)
        const int oc0 = (tid >> 6) * 16;     // 16 output channels per thread
        const float* xb = x   + (size_t)b * CH * NPOS + q0 + i;
        float*       ob = out + (size_t)b * CH * NPOS + q0 + i;
        for (int oc = oc0; oc < oc0 + 16; ++oc) {
            float acc = bp[oc];              // wave-uniform -> scalar loads
#pragma unroll
            for (int c = 0; c < CH; ++c) acc = fmaf(Wp[oc * CH + c], KSs[i][c], acc);
            ob[(size_t)oc * NPOS] = acc + xb[(size_t)oc * NPOS];
        }
    }
}

// ---------------------------------------------------------------------------
extern "C" void kernel_launch(void* const* d_in, const int* in_sizes, int n_in,
                              void* d_out, int out_size, void* d_ws, size_t ws_size,
                              hipStream_t stream) {
    const float* x     = (const float*)d_in[0];
    const float* gamma = (const float*)d_in[1];
    const float* beta  = (const float*)d_in[2];
    const float* Wq    = (const float*)d_in[3];
    const float* bq    = (const float*)d_in[4];
    const float* Wk    = (const float*)d_in[5];
    const float* bk    = (const float*)d_in[6];
    const float* Wv    = (const float*)d_in[7];
    const float* bv    = (const float*)d_in[8];
    const float* Wp    = (const float*)d_in[9];
    const float* bp    = (const float*)d_in[10];
    float* out = (float*)d_out;

    float* ws    = (float*)d_ws;
    float* stats = ws;                                  // 64 floats
    float* q_t   = ws + 256;                            // [B][CH][N]
    float* k_t   = q_t + (size_t)BATCH * CH * NPOS;     // [B][CH][N]
    float* v_t   = k_t + (size_t)BATCH * CH * NPOS;     // [B][CH][N]

    hipLaunchKernelGGL(gn_stats_kernel, dim3(32), dim3(256), 0, stream, x, stats);
    hipLaunchKernelGGL(qkv_gen_kernel, dim3(BATCH * NPOS / 256), dim3(256), 0, stream,
                       x, stats, gamma, beta, Wq, bq, Wk, bk, Wv, bv, q_t, k_t, v_t);
    hipLaunchKernelGGL(attn_flash_kernel, dim3(BATCH * 64), dim3(256), 0, stream,
                       q_t, k_t, v_t, x, Wp, bp, out);
}

// Round 2
// 125.048 us; speedup vs baseline: 5.5730x; 5.5730x over previous
//
#include <hip/hip_runtime.h>
#include <math.h>

#define BATCH 4
#define CH    64
#define NPOS  4096   // 64*64
#define NGRP  8
#define CPG   8      // CH / NGRP
#define GEPS  1e-5f

typedef __attribute__((ext_vector_type(8))) short bf16x8;   // 8 bf16 = 4 VGPRs
typedef __attribute__((ext_vector_type(4))) float f32x4;

// float -> bf16 bits (round-to-nearest-even)
__device__ __forceinline__ ushort f2bf(float f) {
    union { float f; uint32_t u; } v; v.f = f;
    uint32_t r = v.u + 0x7fffu + ((v.u >> 16) & 1u);
    return (ushort)(r >> 16);
}

// XOR swizzle within a 128B row: logical (row, byteInRow) -> physical byte offset
__device__ __forceinline__ uint32_t swz(uint32_t row, uint32_t byteInRow) {
    return (row << 7) + (byteInRow ^ ((row & 7u) << 4));
}

// 16B ds_read of an MFMA fragment slice: row = (m or n) index, kbyte = k-offset in bytes
__device__ __forceinline__ bf16x8 ldfrag(const ushort* base, int row, int kbyte) {
    return *(const bf16x8*)((const char*)base + swz(row, kbyte));
}

__device__ __forceinline__ void gload16(const ushort* g, ushort* l) {
    __builtin_amdgcn_global_load_lds((const __attribute__((address_space(1))) void*)g,
                                     (__attribute__((address_space(3))) void*)l,
                                     16, 0, 0);
}

// Stage a 64-row x 128B tile global->LDS, linear LDS dest, inverse-swizzled
// global source so that swizzled ds_read sees logical layout (rule #21).
__device__ __forceinline__ void stage_tile(const ushort* grow_base, size_t grow_stride,
                                           ushort* lds, int tid) {
#pragma unroll
    for (int i = 0; i < 2; ++i) {
        int L = tid * 16 + i * 4096;
        int row = L >> 7;
        int u = (L >> 4) & 7;
        const ushort* src = grow_base + (size_t)row * grow_stride + (size_t)((u ^ (row & 7)) << 3);
        gload16(src, (ushort*)((char*)lds + L));
    }
}

// ---------------------------------------------------------------------------
// Kernel 1: GroupNorm statistics (one block per (b, g))
// ---------------------------------------------------------------------------
__global__ __launch_bounds__(256) void gn_stats_kernel(const float* __restrict__ x,
                                                       float* __restrict__ stats) {
    const int bg = blockIdx.x;                       // 0..31
    const float4* xp4 = (const float4*)(x + (size_t)bg * CPG * NPOS);
    float s1 = 0.f, s2 = 0.f;
    for (int i = threadIdx.x; i < CPG * NPOS / 4; i += 256) {
        float4 t = xp4[i];
        s1 += t.x + t.y + t.z + t.w;
        s2 += t.x * t.x + t.y * t.y + t.z * t.z + t.w * t.w;
    }
    __shared__ float sh1[256], sh2[256];
    const int tid = threadIdx.x;
    sh1[tid] = s1; sh2[tid] = s2;
    __syncthreads();
    for (int off = 128; off > 0; off >>= 1) {
        if (tid < off) { sh1[tid] += sh1[tid + off]; sh2[tid] += sh2[tid + off]; }
        __syncthreads();
    }
    if (tid == 0) {
        const float inv = 1.0f / (float)(CPG * NPOS);
        float mean = sh1[0] * inv;
        float var  = sh2[0] * inv - mean * mean;
        stats[bg * 2]     = mean;
        stats[bg * 2 + 1] = rsqrtf(var + GEPS);
    }
}

// ---------------------------------------------------------------------------
// Kernel 2: fused GroupNorm + Q/K/V 1x1 convs via MFMA.
// Grid: b(4) * ntile(64). Block 256 = 4 waves. Outputs bf16:
//   q,k : [b][n][c]   v : [b][c][n]
// ---------------------------------------------------------------------------
__global__ __launch_bounds__(256) void qkv_mfma_kernel(
    const float* __restrict__ x, const float* __restrict__ stats,
    const float* __restrict__ gamma, const float* __restrict__ beta,
    const float* __restrict__ Wq, const float* __restrict__ bq,
    const float* __restrict__ Wk, const float* __restrict__ bk,
    const float* __restrict__ Wv, const float* __restrict__ bv,
    ushort* __restrict__ qg, ushort* __restrict__ kg, ushort* __restrict__ vg)
{
    __shared__ ushort xn[64 * 64];     // [n][c] swizzled
    __shared__ ushort Wl[3][64 * 64];  // W row-major [o][c] swizzled, bf16
    __shared__ ushort ob[64 * 64];     // output bounce

    const int tid = threadIdx.x;
    const int w = tid >> 6, lane = tid & 63, g = lane >> 4, q16 = lane & 15;
    const int b = blockIdx.x >> 6, n0 = (blockIdx.x & 63) << 6;

    // ---- stage W matrices as bf16 (swizzled) ----
    {
        const int row = tid >> 2, cb = (tid & 3) << 4;
        const float* Ws[3] = {Wq, Wk, Wv};
#pragma unroll
        for (int m = 0; m < 3; ++m) {
#pragma unroll
            for (int j = 0; j < 4; ++j) {
                float4 v = *(const float4*)(Ws[m] + row * 64 + cb + j * 4);
                ushort4 h; h.x = f2bf(v.x); h.y = f2bf(v.y); h.z = f2bf(v.z); h.w = f2bf(v.w);
                *(ushort4*)((char*)Wl[m] + swz(row, (cb + j * 4) * 2)) = h;
            }
        }
    }
    // ---- stage normalized x tile as xn[n][c] bf16 (swizzled) ----
    {
        const int c = tid >> 2, nb = (tid & 3) << 4;
        const float mean = stats[(b * NGRP + (c >> 3)) * 2];
        const float rstd = stats[(b * NGRP + (c >> 3)) * 2 + 1];
        const float gmm = gamma[c] * rstd;
        const float btt = beta[c] - mean * gmm;
        const float* xp = x + (((size_t)(b * CH + c)) << 12) + n0 + nb;
#pragma unroll
        for (int j = 0; j < 4; ++j) {
            float4 v = *(const float4*)(xp + j * 4);
            float vv[4] = {v.x, v.y, v.z, v.w};
#pragma unroll
            for (int e = 0; e < 4; ++e) {
                int n = nb + j * 4 + e;
                *(ushort*)((char*)xn + swz(n, c * 2)) = f2bf(vv[e] * gmm + btt);
            }
        }
    }
    __syncthreads();

    // ---- q, k:  D[n][o] = xn[n][c] * W^T ----
    bf16x8 ax0 = ldfrag(xn, (w << 4) + q16, (g << 4));
    bf16x8 ax1 = ldfrag(xn, (w << 4) + q16, 64 + (g << 4));
#pragma unroll
    for (int m = 0; m < 2; ++m) {
        const float* bias = m ? bk : bq;
        const float scl = m ? 1.0f : 0.125f;   // fold softmax 1/sqrt(64) into q
#pragma unroll
        for (int ot = 0; ot < 4; ++ot) {
            f32x4 acc = {0.f, 0.f, 0.f, 0.f};
            bf16x8 b0 = ldfrag(Wl[m], (ot << 4) + q16, (g << 4));
            bf16x8 b1 = ldfrag(Wl[m], (ot << 4) + q16, 64 + (g << 4));
            acc = __builtin_amdgcn_mfma_f32_16x16x32_bf16(ax0, b0, acc, 0, 0, 0);
            acc = __builtin_amdgcn_mfma_f32_16x16x32_bf16(ax1, b1, acc, 0, 0, 0);
            float bs = bias[(ot << 4) + q16];
#pragma unroll
            for (int r = 0; r < 4; ++r)
                *(ushort*)((char*)ob + swz((w << 4) + (g << 2) + r, ((ot << 4) + q16) << 1)) =
                    f2bf((acc[r] + bs) * scl);
        }
        __syncthreads();
        // linear store ob rows (=n) -> q/k global [b][n][c]
        ushort* dst = (m ? kg : qg) + (((size_t)b) << 18);   // b*4096*64
#pragma unroll
        for (int i = 0; i < 2; ++i) {
            int L = tid * 16 + i * 4096; int row = L >> 7, u = (L >> 4) & 7;
            int4 d = *(const int4*)((char*)ob + swz(row, u << 4));
            *(int4*)(dst + (size_t)(n0 + row) * 64 + (u << 3)) = d;
        }
        __syncthreads();
    }
    // ---- v:  D[o][n] = Wv * xn^T ----
    {
        bf16x8 aw0 = ldfrag(Wl[2], (w << 4) + q16, (g << 4));
        bf16x8 aw1 = ldfrag(Wl[2], (w << 4) + q16, 64 + (g << 4));
#pragma unroll
        for (int nt = 0; nt < 4; ++nt) {
            f32x4 acc = {0.f, 0.f, 0.f, 0.f};
            bf16x8 b0 = ldfrag(xn, (nt << 4) + q16, (g << 4));
            bf16x8 b1 = ldfrag(xn, (nt << 4) + q16, 64 + (g << 4));
            acc = __builtin_amdgcn_mfma_f32_16x16x32_bf16(aw0, b0, acc, 0, 0, 0);
            acc = __builtin_amdgcn_mfma_f32_16x16x32_bf16(aw1, b1, acc, 0, 0, 0);
#pragma unroll
            for (int r = 0; r < 4; ++r) {
                float bs = bv[(w << 4) + (g << 2) + r];
                *(ushort*)((char*)ob + swz((w << 4) + (g << 2) + r, ((nt << 4) + q16) << 1)) =
                    f2bf(acc[r] + bs);
            }
        }
        __syncthreads();
        ushort* dst = vg + (((size_t)b) << 18);
#pragma unroll
        for (int i = 0; i < 2; ++i) {
            int L = tid * 16 + i * 4096; int row = L >> 7, u = (L >> 4) & 7;
            int4 d = *(const int4*)((char*)ob + swz(row, u << 4));
            *(int4*)(dst + ((size_t)row << 12) + n0 + (u << 3)) = d;   // v [c][n]
        }
    }
}

// ---------------------------------------------------------------------------
// Kernel 3: flash attention (bf16 MFMA) + fused proj + bias + residual.
// Grid: 256 blocks (b * 64 q-tiles of 64). Block 256 = 4 waves; wave w owns
// q rows [16w,16w+16). LDS tiles are [pos][ch]-style 128B rows, XOR-swizzled.
// ---------------------------------------------------------------------------
__global__ __launch_bounds__(256) void attn_mfma_kernel(
    const ushort* __restrict__ qg, const ushort* __restrict__ kg,
    const ushort* __restrict__ vg, const float* __restrict__ x,
    const float* __restrict__ Wp, const float* __restrict__ bp,
    float* __restrict__ out)
{
    __shared__ ushort Qs[64 * 64];      // [q][c]
    __shared__ ushort Ks[2][64 * 64];   // [key][c]
    __shared__ ushort Vs[2][64 * 64];   // [c][key]
    __shared__ ushort Ps[64 * 64];      // [q][key], reused as O [q][c]
    __shared__ ushort Wps[64 * 64];     // Wp [oc][c] bf16

    const int tid = threadIdx.x;
    const int w = tid >> 6, lane = tid & 63, g = lane >> 4, q16 = lane & 15;
    const int b = blockIdx.x >> 6, q0 = (blockIdx.x & 63) << 6;

    const ushort* qb = qg + (((size_t)b) << 18);
    const ushort* kb = kg + (((size_t)b) << 18);
    const ushort* vb = vg + (((size_t)b) << 18);

    // stage Q tile + Wp (once)
    stage_tile(qb + (size_t)q0 * 64, 64, Qs, tid);
    {
        const int row = tid >> 2, cb = (tid & 3) << 4;
#pragma unroll
        for (int j = 0; j < 4; ++j) {
            float4 v = *(const float4*)(Wp + row * 64 + cb + j * 4);
            ushort4 h; h.x = f2bf(v.x); h.y = f2bf(v.y); h.z = f2bf(v.z); h.w = f2bf(v.w);
            *(ushort4*)((char*)Wps + swz(row, (cb + j * 4) * 2)) = h;
        }
    }
    // stage K/V tile 0
    stage_tile(kb, 64, Ks[0], tid);
    stage_tile(vb, 4096, Vs[0], tid);

    float mst[4] = {-1e30f, -1e30f, -1e30f, -1e30f};
    float lst[4] = {0.f, 0.f, 0.f, 0.f};
    f32x4 oacc[4];
#pragma unroll
    for (int ct = 0; ct < 4; ++ct) oacc[ct] = (f32x4){0.f, 0.f, 0.f, 0.f};

    __syncthreads();   // barrier drains vmcnt -> tile 0 resident

    int buf = 0;
    for (int kt = 0; kt < 64; ++kt) {
        if (kt < 63) {   // prefetch next tile into other buffer
            stage_tile(kb + (size_t)(kt + 1) * 64 * 64, 64, Ks[buf ^ 1], tid);
            stage_tile(vb + (size_t)(kt + 1) * 64, 4096, Vs[buf ^ 1], tid);
        }
        // ---- S = Q K^T (C-layout: row=q_local 4g+r, col=key 16nt+q16) ----
        bf16x8 aq0 = ldfrag(Qs, (w << 4) + q16, (g << 4));
        bf16x8 aq1 = ldfrag(Qs, (w << 4) + q16, 64 + (g << 4));
        f32x4 s[4];
#pragma unroll
        for (int nt = 0; nt < 4; ++nt) {
            f32x4 z = {0.f, 0.f, 0.f, 0.f};
            bf16x8 b0 = ldfrag(Ks[buf], (nt << 4) + q16, (g << 4));
            bf16x8 b1 = ldfrag(Ks[buf], (nt << 4) + q16, 64 + (g << 4));
            z = __builtin_amdgcn_mfma_f32_16x16x32_bf16(aq0, b0, z, 0, 0, 0);
            z = __builtin_amdgcn_mfma_f32_16x16x32_bf16(aq1, b1, z, 0, 0, 0);
            s[nt] = z;
        }
        // ---- online softmax (16-lane-group shuffle reduce) ----
        float mnew[4], sc[4];
#pragma unroll
        for (int r = 0; r < 4; ++r) {
            float mx = fmaxf(fmaxf(s[0][r], s[1][r]), fmaxf(s[2][r], s[3][r]));
            mx = fmaxf(mx, __shfl_xor(mx, 1));
            mx = fmaxf(mx, __shfl_xor(mx, 2));
            mx = fmaxf(mx, __shfl_xor(mx, 4));
            mx = fmaxf(mx, __shfl_xor(mx, 8));
            mnew[r] = fmaxf(mst[r], mx);
            sc[r] = __expf(mst[r] - mnew[r]);
            mst[r] = mnew[r];
        }
        float rs[4] = {0.f, 0.f, 0.f, 0.f};
#pragma unroll
        for (int nt = 0; nt < 4; ++nt) {
#pragma unroll
            for (int r = 0; r < 4; ++r) {
                float p = __expf(s[nt][r] - mnew[r]);
                rs[r] += p;
                *(ushort*)((char*)Ps + swz((w << 4) + (g << 2) + r, ((nt << 4) + q16) << 1)) = f2bf(p);
            }
        }
#pragma unroll
        for (int r = 0; r < 4; ++r) {
            rs[r] += __shfl_xor(rs[r], 1);
            rs[r] += __shfl_xor(rs[r], 2);
            rs[r] += __shfl_xor(rs[r], 4);
            rs[r] += __shfl_xor(rs[r], 8);
            lst[r] = lst[r] * sc[r] + rs[r];
        }
#pragma unroll
        for (int ct = 0; ct < 4; ++ct)
#pragma unroll
            for (int r = 0; r < 4; ++r) oacc[ct][r] *= sc[r];
        // ---- O += P V  (A=P from own wave's LDS rows; B=V[c][key]) ----
        bf16x8 pa0 = ldfrag(Ps, (w << 4) + q16, (g << 4));
        bf16x8 pa1 = ldfrag(Ps, (w << 4) + q16, 64 + (g << 4));
#pragma unroll
        for (int ct = 0; ct < 4; ++ct) {
            bf16x8 b0 = ldfrag(Vs[buf], (ct << 4) + q16, (g << 4));
            bf16x8 b1 = ldfrag(Vs[buf], (ct << 4) + q16, 64 + (g << 4));
            oacc[ct] = __builtin_amdgcn_mfma_f32_16x16x32_bf16(pa0, b0, oacc[ct], 0, 0, 0);
            oacc[ct] = __builtin_amdgcn_mfma_f32_16x16x32_bf16(pa1, b1, oacc[ct], 0, 0, 0);
        }
        __syncthreads();   // next tile resident (vmcnt drained) + buf reuse safe
        buf ^= 1;
    }

    // ---- normalize O, dump [q][c] to Ps for the projection GEMM ----
    float linv[4];
#pragma unroll
    for (int r = 0; r < 4; ++r) linv[r] = 1.0f / lst[r];
#pragma unroll
    for (int ct = 0; ct < 4; ++ct)
#pragma unroll
        for (int r = 0; r < 4; ++r)
            *(ushort*)((char*)Ps + swz((w << 4) + (g << 2) + r, ((ct << 4) + q16) << 1)) =
                f2bf(oacc[ct][r] * linv[r]);
    __syncthreads();

    // ---- out[oc][n] = Wp * O^T + bp + x  (wave w owns oc rows 16w..16w+15) ----
    {
        bf16x8 aw0 = ldfrag(Wps, (w << 4) + q16, (g << 4));
        bf16x8 aw1 = ldfrag(Wps, (w << 4) + q16, 64 + (g << 4));
        float bpv[4];
#pragma unroll
        for (int r = 0; r < 4; ++r) bpv[r] = bp[(w << 4) + (g << 2) + r];
#pragma unroll
        for (int qt = 0; qt < 4; ++qt) {
            f32x4 d = {0.f, 0.f, 0.f, 0.f};
            bf16x8 b0 = ldfrag(Ps, (qt << 4) + q16, (g << 4));
            bf16x8 b1 = ldfrag(Ps, (qt << 4) + q16, 64 + (g << 4));
            d = __builtin_amdgcn_mfma_f32_16x16x32_bf16(aw0, b0, d, 0, 0, 0);
            d = __builtin_amdgcn_mfma_f32_16x16x32_bf16(aw1, b1, d, 0, 0, 0);
#pragma unroll
            for (int r = 0; r < 4; ++r) {
                int oc = (w << 4) + (g << 2) + r;
                size_t addr = (((size_t)(b * CH + oc)) << 12) + q0 + (qt << 4) + q16;
                out[addr] = d[r] + bpv[r] + x[addr];
            }
        }
    }
}

// ---------------------------------------------------------------------------
extern "C" void kernel_launch(void* const* d_in, const int* in_sizes, int n_in,
                              void* d_out, int out_size, void* d_ws, size_t ws_size,
                              hipStream_t stream) {
    const float* x     = (const float*)d_in[0];
    const float* gamma = (const float*)d_in[1];
    const float* beta  = (const float*)d_in[2];
    const float* Wq    = (const float*)d_in[3];
    const float* bq    = (const float*)d_in[4];
    const float* Wk    = (const float*)d_in[5];
    const float* bk    = (const float*)d_in[6];
    const float* Wv    = (const float*)d_in[7];
    const float* bv    = (const float*)d_in[8];
    const float* Wp    = (const float*)d_in[9];
    const float* bp    = (const float*)d_in[10];
    float* out = (float*)d_out;

    float* stats = (float*)d_ws;                       // 64 floats
    ushort* q_t = (ushort*)((char*)d_ws + 1024);       // [b][n][c] bf16
    ushort* k_t = q_t + (size_t)BATCH * NPOS * CH;     // [b][n][c] bf16
    ushort* v_t = k_t + (size_t)BATCH * NPOS * CH;     // [b][c][n] bf16

    hipLaunchKernelGGL(gn_stats_kernel, dim3(32), dim3(256), 0, stream, x, stats);
    hipLaunchKernelGGL(qkv_mfma_kernel, dim3(256), dim3(256), 0, stream,
                       x, stats, gamma, beta, Wq, bq, Wk, bk, Wv, bv, q_t, k_t, v_t);
    hipLaunchKernelGGL(attn_mfma_kernel, dim3(256), dim3(256), 0, stream,
                       q_t, k_t, v_t, x, Wp, bp, out);
}

// Round 3
// 70.843 us; speedup vs baseline: 9.8371x; 1.7651x over previous
//
#include <hip/hip_runtime.h>
#include <hip/hip_bf16.h>
#include <math.h>

#define BATCH 4
#define CH    64
#define NPOS  4096   // 64*64
#define NGRP  8
#define CPG   8      // CH / NGRP
#define GEPS  1e-5f
#define NSPLIT 4     // K-dim split of attention
#define LOG2E 1.4426950408889634f

typedef __attribute__((ext_vector_type(8))) short bf16x8;   // 8 bf16 = 4 VGPRs
typedef __attribute__((ext_vector_type(4))) float f32x4;

// float -> bf16 bits (round-to-nearest-even)
__device__ __forceinline__ ushort f2bf(float f) {
    union { float f; uint32_t u; } v; v.f = f;
    uint32_t r = v.u + 0x7fffu + ((v.u >> 16) & 1u);
    return (ushort)(r >> 16);
}

// XOR swizzle within a 128B row: logical (row, byteInRow) -> physical byte offset
__device__ __forceinline__ uint32_t swz(uint32_t row, uint32_t byteInRow) {
    return (row << 7) + (byteInRow ^ ((row & 7u) << 4));
}

// 16B ds_read of an MFMA fragment slice
__device__ __forceinline__ bf16x8 ldfrag(const ushort* base, int row, int kbyte) {
    return *(const bf16x8*)((const char*)base + swz(row, kbyte));
}

__device__ __forceinline__ void gload16(const ushort* g, ushort* l) {
    __builtin_amdgcn_global_load_lds((const __attribute__((address_space(1))) void*)g,
                                     (__attribute__((address_space(3))) void*)l,
                                     16, 0, 0);
}

// Stage a 64-row x 128B tile global->LDS, linear LDS dest, inverse-swizzled
// global source so that swizzled ds_read sees logical layout.
__device__ __forceinline__ void stage_tile(const ushort* grow_base, size_t grow_stride,
                                           ushort* lds, int tid) {
#pragma unroll
    for (int i = 0; i < 2; ++i) {
        int L = tid * 16 + i * 4096;
        int row = L >> 7;
        int u = (L >> 4) & 7;
        const ushort* src = grow_base + (size_t)row * grow_stride + (size_t)((u ^ (row & 7)) << 3);
        gload16(src, (ushort*)((char*)lds + L));
    }
}

// ---------------------------------------------------------------------------
// Kernel 1: GroupNorm statistics (one block per (b, g))
// ---------------------------------------------------------------------------
__global__ __launch_bounds__(256) void gn_stats_kernel(const float* __restrict__ x,
                                                       float* __restrict__ stats) {
    const int bg = blockIdx.x;                       // 0..31
    const float4* xp4 = (const float4*)(x + (size_t)bg * CPG * NPOS);
    float s1 = 0.f, s2 = 0.f;
    for (int i = threadIdx.x; i < CPG * NPOS / 4; i += 256) {
        float4 t = xp4[i];
        s1 += t.x + t.y + t.z + t.w;
        s2 += t.x * t.x + t.y * t.y + t.z * t.z + t.w * t.w;
    }
    __shared__ float sh1[256], sh2[256];
    const int tid = threadIdx.x;
    sh1[tid] = s1; sh2[tid] = s2;
    __syncthreads();
    for (int off = 128; off > 0; off >>= 1) {
        if (tid < off) { sh1[tid] += sh1[tid + off]; sh2[tid] += sh2[tid + off]; }
        __syncthreads();
    }
    if (tid == 0) {
        const float inv = 1.0f / (float)(CPG * NPOS);
        float mean = sh1[0] * inv;
        float var  = sh2[0] * inv - mean * mean;
        stats[bg * 2]     = mean;
        stats[bg * 2 + 1] = rsqrtf(var + GEPS);
    }
}

// ---------------------------------------------------------------------------
// Kernel 2: fused GroupNorm + Q/K/V 1x1 convs via MFMA (unchanged, proven).
// Outputs bf16:  q,k : [b][n][c]   v : [b][c][n]
// q folds (bias + 0.125*log2e) so softmax runs in exp2 domain.
// ---------------------------------------------------------------------------
__global__ __launch_bounds__(256) void qkv_mfma_kernel(
    const float* __restrict__ x, const float* __restrict__ stats,
    const float* __restrict__ gamma, const float* __restrict__ beta,
    const float* __restrict__ Wq, const float* __restrict__ bq,
    const float* __restrict__ Wk, const float* __restrict__ bk,
    const float* __restrict__ Wv, const float* __restrict__ bv,
    ushort* __restrict__ qg, ushort* __restrict__ kg, ushort* __restrict__ vg)
{
    __shared__ ushort xn[64 * 64];     // [n][c] swizzled
    __shared__ ushort Wl[3][64 * 64];  // W row-major [o][c] swizzled, bf16
    __shared__ ushort ob[64 * 64];     // output bounce

    const int tid = threadIdx.x;
    const int w = tid >> 6, lane = tid & 63, g = lane >> 4, q16 = lane & 15;
    const int b = blockIdx.x >> 6, n0 = (blockIdx.x & 63) << 6;

    {
        const int row = tid >> 2, cb = (tid & 3) << 4;
        const float* Ws[3] = {Wq, Wk, Wv};
#pragma unroll
        for (int m = 0; m < 3; ++m) {
#pragma unroll
            for (int j = 0; j < 4; ++j) {
                float4 v = *(const float4*)(Ws[m] + row * 64 + cb + j * 4);
                ushort4 h; h.x = f2bf(v.x); h.y = f2bf(v.y); h.z = f2bf(v.z); h.w = f2bf(v.w);
                *(ushort4*)((char*)Wl[m] + swz(row, (cb + j * 4) * 2)) = h;
            }
        }
    }
    {
        const int c = tid >> 2, nb = (tid & 3) << 4;
        const float mean = stats[(b * NGRP + (c >> 3)) * 2];
        const float rstd = stats[(b * NGRP + (c >> 3)) * 2 + 1];
        const float gmm = gamma[c] * rstd;
        const float btt = beta[c] - mean * gmm;
        const float* xp = x + (((size_t)(b * CH + c)) << 12) + n0 + nb;
#pragma unroll
        for (int j = 0; j < 4; ++j) {
            float4 v = *(const float4*)(xp + j * 4);
            float vv[4] = {v.x, v.y, v.z, v.w};
#pragma unroll
            for (int e = 0; e < 4; ++e) {
                int n = nb + j * 4 + e;
                *(ushort*)((char*)xn + swz(n, c * 2)) = f2bf(vv[e] * gmm + btt);
            }
        }
    }
    __syncthreads();

    bf16x8 ax0 = ldfrag(xn, (w << 4) + q16, (g << 4));
    bf16x8 ax1 = ldfrag(xn, (w << 4) + q16, 64 + (g << 4));
#pragma unroll
    for (int m = 0; m < 2; ++m) {
        const float* bias = m ? bk : bq;
        const float scl = m ? 1.0f : 0.125f * LOG2E;   // q in exp2 domain
#pragma unroll
        for (int ot = 0; ot < 4; ++ot) {
            f32x4 acc = {0.f, 0.f, 0.f, 0.f};
            bf16x8 b0 = ldfrag(Wl[m], (ot << 4) + q16, (g << 4));
            bf16x8 b1 = ldfrag(Wl[m], (ot << 4) + q16, 64 + (g << 4));
            acc = __builtin_amdgcn_mfma_f32_16x16x32_bf16(ax0, b0, acc, 0, 0, 0);
            acc = __builtin_amdgcn_mfma_f32_16x16x32_bf16(ax1, b1, acc, 0, 0, 0);
            float bs = bias[(ot << 4) + q16];
#pragma unroll
            for (int r = 0; r < 4; ++r)
                *(ushort*)((char*)ob + swz((w << 4) + (g << 2) + r, ((ot << 4) + q16) << 1)) =
                    f2bf((acc[r] + bs) * scl);
        }
        __syncthreads();
        ushort* dst = (m ? kg : qg) + (((size_t)b) << 18);
#pragma unroll
        for (int i = 0; i < 2; ++i) {
            int L = tid * 16 + i * 4096; int row = L >> 7, u = (L >> 4) & 7;
            int4 d = *(const int4*)((char*)ob + swz(row, u << 4));
            *(int4*)(dst + (size_t)(n0 + row) * 64 + (u << 3)) = d;
        }
        __syncthreads();
    }
    {
        bf16x8 aw0 = ldfrag(Wl[2], (w << 4) + q16, (g << 4));
        bf16x8 aw1 = ldfrag(Wl[2], (w << 4) + q16, 64 + (g << 4));
#pragma unroll
        for (int nt = 0; nt < 4; ++nt) {
            f32x4 acc = {0.f, 0.f, 0.f, 0.f};
            bf16x8 b0 = ldfrag(xn, (nt << 4) + q16, (g << 4));
            bf16x8 b1 = ldfrag(xn, (nt << 4) + q16, 64 + (g << 4));
            acc = __builtin_amdgcn_mfma_f32_16x16x32_bf16(aw0, b0, acc, 0, 0, 0);
            acc = __builtin_amdgcn_mfma_f32_16x16x32_bf16(aw1, b1, acc, 0, 0, 0);
#pragma unroll
            for (int r = 0; r < 4; ++r) {
                float bs = bv[(w << 4) + (g << 2) + r];
                *(ushort*)((char*)ob + swz((w << 4) + (g << 2) + r, ((nt << 4) + q16) << 1)) =
                    f2bf(acc[r] + bs);
            }
        }
        __syncthreads();
        ushort* dst = vg + (((size_t)b) << 18);
#pragma unroll
        for (int i = 0; i < 2; ++i) {
            int L = tid * 16 + i * 4096; int row = L >> 7, u = (L >> 4) & 7;
            int4 d = *(const int4*)((char*)ob + swz(row, u << 4));
            *(int4*)(dst + ((size_t)row << 12) + n0 + (u << 3)) = d;   // v [c][n]
        }
    }
}

// ---------------------------------------------------------------------------
// Kernel 3: flash attention, swapped QK^T (S^T = K·Q^T), K-split x4.
// Grid 1024 = b(4) x qtile(64) x ksplit(4); 256 thr = 4 waves; wave w owns
// q rows [16w,16w+16). Each lane owns ONE q column (q16) -> per-lane scalar
// m/l, softmax reduce = in-lane tree + 2 shuffles. Writes unnormalized
// partial O~^T [b][ks][c][n] f32 + (m,l) per (b,ks,n).
// ---------------------------------------------------------------------------
__global__ __launch_bounds__(256, 4) void attn_mfma_kernel(
    const ushort* __restrict__ qg, const ushort* __restrict__ kg,
    const ushort* __restrict__ vg,
    float* __restrict__ opart, float* __restrict__ ml)
{
    __shared__ ushort QPs[64 * 64];     // Q staging, then per-wave P rows
    __shared__ ushort Ks[2][64 * 64];   // [key][c]
    __shared__ ushort Vs[2][64 * 64];   // [c][key]

    const int tid = threadIdx.x;
    const int w = tid >> 6, lane = tid & 63, lg = lane >> 4, q16 = lane & 15;
    const int ks = blockIdx.x & 3;
    const int qt_ = (blockIdx.x >> 2) & 63;
    const int b = blockIdx.x >> 8;
    const int q0 = qt_ << 6;
    const int k0 = ks << 10;            // 1024 keys per split

    const ushort* qb = qg + (((size_t)b) << 18);
    const ushort* kb = kg + (((size_t)b) << 18);
    const ushort* vb = vg + (((size_t)b) << 18);

    stage_tile(qb + (size_t)q0 * 64, 64, QPs, tid);
    stage_tile(kb + (size_t)k0 * 64, 64, Ks[0], tid);
    stage_tile(vb + k0, 4096, Vs[0], tid);

    float mst = -1e30f, lst = 0.0f;     // per-lane: one q row each
    f32x4 oacc[4];
#pragma unroll
    for (int ct = 0; ct < 4; ++ct) oacc[ct] = (f32x4){0.f, 0.f, 0.f, 0.f};

    __syncthreads();

    // hoist Q fragments (rows are per-wave private; QPs rows reused for P)
    const bf16x8 aq0 = ldfrag(QPs, (w << 4) + q16, (lg << 4));
    const bf16x8 aq1 = ldfrag(QPs, (w << 4) + q16, 64 + (lg << 4));
    const int prow = (w << 4) + q16;

    int buf = 0;
    for (int kt = 0; kt < 16; ++kt) {
        if (kt < 15) {
            stage_tile(kb + (size_t)(k0 + (kt + 1) * 64) * 64, 64, Ks[buf ^ 1], tid);
            stage_tile(vb + k0 + (kt + 1) * 64, 4096, Vs[buf ^ 1], tid);
        }
        // ---- S^T = K·Q^T : lane holds keys {16nt+4lg+r}, col q = 16w+q16 ----
        f32x4 s[4];
#pragma unroll
        for (int nt = 0; nt < 4; ++nt) {
            f32x4 z = {0.f, 0.f, 0.f, 0.f};
            bf16x8 a0 = ldfrag(Ks[buf], (nt << 4) + q16, (lg << 4));
            bf16x8 a1 = ldfrag(Ks[buf], (nt << 4) + q16, 64 + (lg << 4));
            z = __builtin_amdgcn_mfma_f32_16x16x32_bf16(a0, aq0, z, 0, 0, 0);
            z = __builtin_amdgcn_mfma_f32_16x16x32_bf16(a1, aq1, z, 0, 0, 0);
            s[nt] = z;
        }
        // ---- softmax (exp2 domain): in-lane tree + xor16/xor32 ----
        float mx;
        {
            float m0 = fmaxf(fmaxf(s[0][0], s[0][1]), fmaxf(s[0][2], s[0][3]));
            float m1 = fmaxf(fmaxf(s[1][0], s[1][1]), fmaxf(s[1][2], s[1][3]));
            float m2 = fmaxf(fmaxf(s[2][0], s[2][1]), fmaxf(s[2][2], s[2][3]));
            float m3 = fmaxf(fmaxf(s[3][0], s[3][1]), fmaxf(s[3][2], s[3][3]));
            mx = fmaxf(fmaxf(m0, m1), fmaxf(m2, m3));
        }
        mx = fmaxf(mx, __shfl_xor(mx, 16));
        mx = fmaxf(mx, __shfl_xor(mx, 32));
        const float mnew = fmaxf(mst, mx);
        const float sc = exp2f(mst - mnew);
        mst = mnew;

        float p[4][4];
        float rs = 0.0f;
#pragma unroll
        for (int nt = 0; nt < 4; ++nt)
#pragma unroll
            for (int r = 0; r < 4; ++r) {
                float pv = exp2f(s[nt][r] - mnew);
                p[nt][r] = pv;
                rs += pv;
            }
        rs += __shfl_xor(rs, 16);
        rs += __shfl_xor(rs, 32);
        lst = lst * sc + rs;
#pragma unroll
        for (int ct = 0; ct < 4; ++ct)
#pragma unroll
            for (int r = 0; r < 4; ++r) oacc[ct][r] *= sc;

        // ---- pack P pairs -> own row of QPs: [q][key] (8 x b32 writes) ----
#pragma unroll
        for (int nt = 0; nt < 4; ++nt)
#pragma unroll
            for (int h2 = 0; h2 < 2; ++h2) {
                float2 t; t.x = p[nt][2 * h2]; t.y = p[nt][2 * h2 + 1];
                __hip_bfloat162 bb = __float22bfloat162_rn(t);
                *(uint32_t*)((char*)QPs + swz(prow, (nt << 5) + (lg << 3) + (h2 << 2))) =
                    *(uint32_t*)&bb;
            }
        asm volatile("" ::: "memory");   // keep P writes before P reads
        // ---- O^T += V^T · P^T ----
        bf16x8 pb0 = ldfrag(QPs, prow, (lg << 4));
        bf16x8 pb1 = ldfrag(QPs, prow, 64 + (lg << 4));
#pragma unroll
        for (int ct = 0; ct < 4; ++ct) {
            bf16x8 v0 = ldfrag(Vs[buf], (ct << 4) + q16, (lg << 4));
            bf16x8 v1 = ldfrag(Vs[buf], (ct << 4) + q16, 64 + (lg << 4));
            oacc[ct] = __builtin_amdgcn_mfma_f32_16x16x32_bf16(v0, pb0, oacc[ct], 0, 0, 0);
            oacc[ct] = __builtin_amdgcn_mfma_f32_16x16x32_bf16(v1, pb1, oacc[ct], 0, 0, 0);
        }
        __syncthreads();
        buf ^= 1;
    }

    // ---- store unnormalized partial O~^T[c][n] + (m,l) ----
    const int n = q0 + (w << 4) + q16;
    float* obase = opart + ((((size_t)(b * NSPLIT + ks)) * 64) << 12) + n;
#pragma unroll
    for (int ct = 0; ct < 4; ++ct)
#pragma unroll
        for (int r = 0; r < 4; ++r)
            obase[((size_t)((ct << 4) + (lg << 2) + r)) << 12] = oacc[ct][r];
    if (lg == 0) {
        ml[(((size_t)(b * NSPLIT + ks)) * 2 + 0) * 4096 + n] = mst;
        ml[(((size_t)(b * NSPLIT + ks)) * 2 + 1) * 4096 + n] = lst;
    }
}

// ---------------------------------------------------------------------------
// Kernel 4: split-combine + output projection + bias + residual.
// Grid 256 = b(4) x ntile(64); 256 thr = 4 waves.
// ---------------------------------------------------------------------------
__global__ __launch_bounds__(256) void combine_kernel(
    const float* __restrict__ opart, const float* __restrict__ ml,
    const float* __restrict__ x, const float* __restrict__ Wp,
    const float* __restrict__ bp, float* __restrict__ out)
{
    __shared__ ushort Obf[64 * 64];    // combined O [n][c] bf16 swizzled
    __shared__ ushort Wps[64 * 64];    // Wp [oc][c] bf16 swizzled
    __shared__ float as_[NSPLIT][64];  // per-split weight per n_local

    const int tid = threadIdx.x;
    const int w = tid >> 6, lane = tid & 63, g = lane >> 4, q16 = lane & 15;
    const int b = blockIdx.x >> 6, n0 = (blockIdx.x & 63) << 6;

    // stage Wp as bf16 swizzled
    {
        const int row = tid >> 2, cb = (tid & 3) << 4;
#pragma unroll
        for (int j = 0; j < 4; ++j) {
            float4 v = *(const float4*)(Wp + row * 64 + cb + j * 4);
            ushort4 h; h.x = f2bf(v.x); h.y = f2bf(v.y); h.z = f2bf(v.z); h.w = f2bf(v.w);
            *(ushort4*)((char*)Wps + swz(row, (cb + j * 4) * 2)) = h;
        }
    }
    // per-n combine weights
    if (tid < 64) {
        const int n = n0 + tid;
        float m[NSPLIT], l[NSPLIT];
#pragma unroll
        for (int s = 0; s < NSPLIT; ++s) {
            m[s] = ml[(((size_t)(b * NSPLIT + s)) * 2 + 0) * 4096 + n];
            l[s] = ml[(((size_t)(b * NSPLIT + s)) * 2 + 1) * 4096 + n];
        }
        float mm = fmaxf(fmaxf(m[0], m[1]), fmaxf(m[2], m[3]));
        float wv[NSPLIT], denom = 0.f;
#pragma unroll
        for (int s = 0; s < NSPLIT; ++s) { wv[s] = exp2f(m[s] - mm); denom += wv[s] * l[s]; }
        float inv = 1.0f / denom;
#pragma unroll
        for (int s = 0; s < NSPLIT; ++s) as_[s][tid] = wv[s] * inv;
    }
    __syncthreads();

    // combine splits: thread owns (c = tid>>2, 16 n's at nb=(tid&3)*16)
    {
        const int c = tid >> 2, nb = (tid & 3) << 4;
        const float* base = opart + ((((size_t)(b * NSPLIT)) * 64 + c) << 12) + n0 + nb;
        const size_t sstride = (size_t)64 << 12;   // split stride in floats
#pragma unroll
        for (int j4 = 0; j4 < 4; ++j4) {
            float4 o0 = *(const float4*)(base + 0 * sstride + j4 * 4);
            float4 o1 = *(const float4*)(base + 1 * sstride + j4 * 4);
            float4 o2 = *(const float4*)(base + 2 * sstride + j4 * 4);
            float4 o3 = *(const float4*)(base + 3 * sstride + j4 * 4);
            float a0[4] = {o0.x, o0.y, o0.z, o0.w};
            float a1[4] = {o1.x, o1.y, o1.z, o1.w};
            float a2[4] = {o2.x, o2.y, o2.z, o2.w};
            float a3[4] = {o3.x, o3.y, o3.z, o3.w};
#pragma unroll
            for (int e = 0; e < 4; ++e) {
                int nl = nb + j4 * 4 + e;
                float val = as_[0][nl] * a0[e] + as_[1][nl] * a1[e]
                          + as_[2][nl] * a2[e] + as_[3][nl] * a3[e];
                *(ushort*)((char*)Obf + swz(nl, c << 1)) = f2bf(val);
            }
        }
    }
    __syncthreads();

    // projection GEMM + bias + residual (verified epilogue structure)
    {
        bf16x8 aw0 = ldfrag(Wps, (w << 4) + q16, (g << 4));
        bf16x8 aw1 = ldfrag(Wps, (w << 4) + q16, 64 + (g << 4));
        float bpv[4];
#pragma unroll
        for (int r = 0; r < 4; ++r) bpv[r] = bp[(w << 4) + (g << 2) + r];
#pragma unroll
        for (int qt = 0; qt < 4; ++qt) {
            f32x4 d = {0.f, 0.f, 0.f, 0.f};
            bf16x8 b0 = ldfrag(Obf, (qt << 4) + q16, (g << 4));
            bf16x8 b1 = ldfrag(Obf, (qt << 4) + q16, 64 + (g << 4));
            d = __builtin_amdgcn_mfma_f32_16x16x32_bf16(aw0, b0, d, 0, 0, 0);
            d = __builtin_amdgcn_mfma_f32_16x16x32_bf16(aw1, b1, d, 0, 0, 0);
#pragma unroll
            for (int r = 0; r < 4; ++r) {
                int oc = (w << 4) + (g << 2) + r;
                size_t addr = (((size_t)(b * CH + oc)) << 12) + n0 + (qt << 4) + q16;
                out[addr] = d[r] + bpv[r] + x[addr];
            }
        }
    }
}

// ---------------------------------------------------------------------------
extern "C" void kernel_launch(void* const* d_in, const int* in_sizes, int n_in,
                              void* d_out, int out_size, void* d_ws, size_t ws_size,
                              hipStream_t stream) {
    const float* x     = (const float*)d_in[0];
    const float* gamma = (const float*)d_in[1];
    const float* beta  = (const float*)d_in[2];
    const float* Wq    = (const float*)d_in[3];
    const float* bq    = (const float*)d_in[4];
    const float* Wk    = (const float*)d_in[5];
    const float* bk    = (const float*)d_in[6];
    const float* Wv    = (const float*)d_in[7];
    const float* bv    = (const float*)d_in[8];
    const float* Wp    = (const float*)d_in[9];
    const float* bp    = (const float*)d_in[10];
    float* out = (float*)d_out;

    float* stats = (float*)d_ws;                       // 64 floats
    ushort* q_t = (ushort*)((char*)d_ws + 1024);       // [b][n][c] bf16, 2MB
    ushort* k_t = q_t + (size_t)BATCH * NPOS * CH;     // [b][n][c] bf16, 2MB
    ushort* v_t = k_t + (size_t)BATCH * NPOS * CH;     // [b][c][n] bf16, 2MB
    float* opart = (float*)((char*)d_ws + 1024 + (size_t)3 * BATCH * NPOS * CH * 2);
    float* ml    = opart + (size_t)BATCH * NSPLIT * CH * NPOS;   // after 16MB

    hipLaunchKernelGGL(gn_stats_kernel, dim3(32), dim3(256), 0, stream, x, stats);
    hipLaunchKernelGGL(qkv_mfma_kernel, dim3(256), dim3(256), 0, stream,
                       x, stats, gamma, beta, Wq, bq, Wk, bk, Wv, bv, q_t, k_t, v_t);
    hipLaunchKernelGGL(attn_mfma_kernel, dim3(BATCH * 64 * NSPLIT), dim3(256), 0, stream,
                       q_t, k_t, v_t, opart, ml);
    hipLaunchKernelGGL(combine_kernel, dim3(BATCH * 64), dim3(256), 0, stream,
                       opart, ml, x, Wp, bp, out);
}